// Round 2
// baseline (1050.575 us; speedup 1.0000x reference)
//
#include <hip/hip_runtime.h>
#include <hip/hip_bf16.h>

// ---------------------------------------------------------------------------
// rnn_decoder: B=256 T=256 H=1024 E=512 V=32000 BN=512
// out = [pred (256x32000) | h1 (2x256x1024) | attn (256x256)]  (f32)
// All GEMMs bf16 MFMA (16x16x32), consistent assumed k-mapping for A and B
// fragments => correctness independent of HW internal K ordering. C layout:
// col=lane&15, row=(lane>>4)*4+reg (HW-verified m89).
// ---------------------------------------------------------------------------

typedef unsigned short u16;
typedef unsigned int u32;
typedef float f32x4 __attribute__((ext_vector_type(4)));
typedef __bf16 bf16x8 __attribute__((ext_vector_type(8)));
typedef short s16x8 __attribute__((ext_vector_type(8)));

__device__ __forceinline__ u16 f2bf(float x) {
  u32 u = __float_as_uint(x);
  u += 0x7fffu + ((u >> 16) & 1u);
  return (u16)(u >> 16);
}
__device__ __forceinline__ u32 pack2(float a, float b) {
  return (u32)f2bf(a) | ((u32)f2bf(b) << 16);
}
__device__ __forceinline__ f32x4 mfma_bf16(s16x8 a, s16x8 b, f32x4 c) {
  union { s16x8 s; bf16x8 b; } ua, ub;
  ua.s = a; ub.s = b;
  return __builtin_amdgcn_mfma_f32_16x16x32_bf16(ua.b, ub.b, c, 0, 0, 0);
}
__device__ __forceinline__ void gll16(const void* g, void* l) {
  __builtin_amdgcn_global_load_lds((__attribute__((address_space(1))) void*)g,
                                   (__attribute__((address_space(3))) void*)l,
                                   16, 0, 0);
}
__device__ __forceinline__ float sigf(float x) { return 1.0f / (1.0f + __expf(-x)); }

// ---------------------------------------------------------------------------
// Big fused kernel: scores[m] = sum_h tanh( (ctx @ weT^T)[m][h] + qd[b][h] ) * v[h]
// ctx (65536,2048) f32, weT (1024,2048) bf16, grid.x = 1024 (BM=64), block 512.
// Wave tile 64m x 128n (acc 4x8 frags). B staged via global_load_lds (dbuf
// 2x64KB); A reg-staged f32->bf16 (dbuf 2x4KB).
// ---------------------------------------------------------------------------
#define SCORES_LDS 149504
__global__ __launch_bounds__(512, 2) void k_scores(
    const float* __restrict__ ctx, const u16* __restrict__ weT,
    const float* __restrict__ qd, const float* __restrict__ att_v,
    float* __restrict__ scores)
{
  extern __shared__ __align__(16) char smem[];
  u16*   Bs  = (u16*)smem;               // [2][32768] u16 (2 x 64KB)
  u16*   As  = (u16*)(smem + 131072);    // [2][2048]  u16 (2 x 4KB)
  float* vq  = (float*)(smem + 139264);  // [2048]: v | qd[b]
  float* red = (float*)(smem + 147456);  // [64][8]

  const int tid = threadIdx.x;
  const int lane = tid & 63, wid = tid >> 6;
  const int l15 = lane & 15, lg = lane >> 4;
  const int m0 = blockIdx.x * 64;
  const int b = m0 >> 8;

  for (int i = tid; i < 2048; i += 512)
    vq[i] = (i < 1024) ? att_v[i] : qd[(size_t)b * 1024 + (i - 1024)];

  // A staging coords: 64 rows x 8 float4-cols
  const int arow = tid >> 3, ac = tid & 7;
  const float* aptr = ctx + (size_t)(m0 + arow) * 2048 + ac * 4;
  const int awoff = arow * 32 + ac * 4;  // u16 units

  // B gll source offsets (u16 units), j=0..7: row = wid*128 + j*16 + lane/4
  size_t bsrc[8];
#pragma unroll
  for (int j = 0; j < 8; ++j)
    bsrc[j] = (size_t)(wid * 128 + j * 16 + (lane >> 2)) * 2048 + (size_t)(lane & 3) * 8;

  int aoff[4], boff[8];
#pragma unroll
  for (int mf = 0; mf < 4; ++mf) aoff[mf] = (mf * 16 + l15) * 32 + lg * 8;
#pragma unroll
  for (int nf = 0; nf < 8; ++nf) boff[nf] = (wid * 128 + nf * 16 + l15) * 32 + lg * 8;

  f32x4 acc[4][8];
#pragma unroll
  for (int mf = 0; mf < 4; ++mf)
#pragma unroll
    for (int nf = 0; nf < 8; ++nf) acc[mf][nf] = (f32x4){0.f, 0.f, 0.f, 0.f};

  // prologue: stage kt=0 into buffer 0
  {
#pragma unroll
    for (int j = 0; j < 8; ++j)
      gll16(weT + bsrc[j], Bs + wid * 4096 + j * 512);
    float4 av = *(const float4*)aptr;
    u32* w = (u32*)(As + awoff);
    w[0] = pack2(av.x, av.y); w[1] = pack2(av.z, av.w);
  }
  __syncthreads();

  for (int kt = 0; kt < 64; ++kt) {
    const int cur = kt & 1, nxt = cur ^ 1;
    const bool pf = (kt < 63);
    float4 av;
    if (pf) {
#pragma unroll
      for (int j = 0; j < 8; ++j)
        gll16(weT + bsrc[j] + (size_t)(kt + 1) * 32, Bs + nxt * 32768 + wid * 4096 + j * 512);
      av = *(const float4*)(aptr + (size_t)(kt + 1) * 32);
    }
    s16x8 af[4], bf[8];
#pragma unroll
    for (int mf = 0; mf < 4; ++mf) af[mf] = *(const s16x8*)(As + cur * 2048 + aoff[mf]);
#pragma unroll
    for (int nf = 0; nf < 8; ++nf) bf[nf] = *(const s16x8*)(Bs + cur * 32768 + boff[nf]);
#pragma unroll
    for (int nf = 0; nf < 8; ++nf)
#pragma unroll
      for (int mf = 0; mf < 4; ++mf)
        acc[mf][nf] = mfma_bf16(af[mf], bf[nf], acc[mf][nf]);
    if (pf) {
      u32* w = (u32*)(As + nxt * 2048 + awoff);
      w[0] = pack2(av.x, av.y); w[1] = pack2(av.z, av.w);
    }
    __syncthreads();
  }

  // epilogue: tanh(acc + qd) * v, reduce over n
  float rp[4][4] = {{0.f, 0.f, 0.f, 0.f}, {0.f, 0.f, 0.f, 0.f},
                    {0.f, 0.f, 0.f, 0.f}, {0.f, 0.f, 0.f, 0.f}};
#pragma unroll
  for (int mf = 0; mf < 4; ++mf)
#pragma unroll
    for (int nf = 0; nf < 8; ++nf) {
      int col = wid * 128 + nf * 16 + l15;
      float vv = vq[col], qv = vq[1024 + col];
#pragma unroll
      for (int e = 0; e < 4; ++e)
        rp[mf][e] += tanhf(acc[mf][nf][e] + qv) * vv;
    }
#pragma unroll
  for (int d = 1; d < 16; d <<= 1)
#pragma unroll
    for (int mf = 0; mf < 4; ++mf)
#pragma unroll
      for (int e = 0; e < 4; ++e)
        rp[mf][e] += __shfl_xor(rp[mf][e], d);
  if (l15 == 0) {
#pragma unroll
    for (int mf = 0; mf < 4; ++mf)
#pragma unroll
      for (int e = 0; e < 4; ++e)
        red[(mf * 16 + lg * 4 + e) * 8 + wid] = rp[mf][e];
  }
  __syncthreads();
  if (tid < 64) {
    float s = 0.f;
#pragma unroll
    for (int w = 0; w < 8; ++w) s += red[tid * 8 + w];
    scores[(size_t)m0 + tid] = s;
  }
}

// ---------------------------------------------------------------------------
// Generic small GEMM: C[M=256,N] (+)= A(bf16,(256,K)) @ W^T
//   MODE 0: W is (N,K) f32 row-major (weights stored (out,in))
//   MODE 1: W is (K,N) f32 row-major (standard (in,out))
// Tile: BM=256 (full M), BN=64, BK=32. 4 waves, wave tile 64m x 64n.
// split-K via blockIdx.z -> atomicAdd into pre-zeroed C (atomic_mode=1),
// else direct store (+bias).
// MODE 1 staging: each thread loads TWO float4 col-groups (b_c4*4 and
// 32+b_c4*4) so all 64 Bs rows are covered (round-1 bugfix).
// ---------------------------------------------------------------------------
template <int MODE>
__global__ __launch_bounds__(256, 2) void k_gemm(
    const u16* __restrict__ A, const float* __restrict__ W,
    float* __restrict__ C, const float* __restrict__ bias,
    int N, int K, int ksteps_per, int tot_ksteps, int atomic_mode)
{
  __shared__ u16 As[2][8192];  // 256 x 32
  __shared__ u16 Bs[2][2048];  // 64 x 32
  const int tid = threadIdx.x, lane = tid & 63, wid = tid >> 6;
  const int l15 = lane & 15, lg = lane >> 4;
  const int m0 = blockIdx.x * 256;
  const int n0 = blockIdx.y * 64;
  const int kc0 = blockIdx.z * ksteps_per;
  int kcn = tot_ksteps - kc0;
  if (kcn > ksteps_per) kcn = ksteps_per;

  size_t asrc[4];
#pragma unroll
  for (int j = 0; j < 4; ++j)
    asrc[j] = (size_t)(m0 + wid * 64 + j * 16 + (lane >> 2)) * K + (size_t)(lane & 3) * 8;
  int aoff[4], boff[4];
#pragma unroll
  for (int mf = 0; mf < 4; ++mf) aoff[mf] = (wid * 64 + mf * 16 + l15) * 32 + lg * 8;
#pragma unroll
  for (int nf = 0; nf < 4; ++nf) boff[nf] = (nf * 16 + l15) * 32 + lg * 8;

  // B staging coords
  const int b_row = tid >> 2, b_c8 = tid & 3;   // MODE 0
  const int b_kk = tid >> 3, b_c4 = tid & 7;    // MODE 1

  f32x4 acc[4][4];
#pragma unroll
  for (int mf = 0; mf < 4; ++mf)
#pragma unroll
    for (int nf = 0; nf < 4; ++nf) acc[mf][nf] = (f32x4){0.f, 0.f, 0.f, 0.f};

  // prologue stage kt=kc0 into buf 0
  {
#pragma unroll
    for (int j = 0; j < 4; ++j)
      gll16(A + asrc[j] + (size_t)kc0 * 32, &As[0][wid * 2048 + j * 512]);
    if (MODE == 0) {
      const float* p = W + (size_t)(n0 + b_row) * K + (size_t)kc0 * 32 + b_c8 * 8;
      float4 v0 = *(const float4*)p, v1 = *(const float4*)(p + 4);
      u32* w = (u32*)&Bs[0][b_row * 32 + b_c8 * 8];
      w[0] = pack2(v0.x, v0.y); w[1] = pack2(v0.z, v0.w);
      w[2] = pack2(v1.x, v1.y); w[3] = pack2(v1.z, v1.w);
    } else {
      const float* p = W + (size_t)(kc0 * 32 + b_kk) * N + n0 + b_c4 * 4;
      float4 v0 = *(const float4*)p;
      float4 v1 = *(const float4*)(p + 32);
      int r0 = b_c4 * 4, r1 = 32 + b_c4 * 4;
      Bs[0][(r0 + 0) * 32 + b_kk] = f2bf(v0.x);
      Bs[0][(r0 + 1) * 32 + b_kk] = f2bf(v0.y);
      Bs[0][(r0 + 2) * 32 + b_kk] = f2bf(v0.z);
      Bs[0][(r0 + 3) * 32 + b_kk] = f2bf(v0.w);
      Bs[0][(r1 + 0) * 32 + b_kk] = f2bf(v1.x);
      Bs[0][(r1 + 1) * 32 + b_kk] = f2bf(v1.y);
      Bs[0][(r1 + 2) * 32 + b_kk] = f2bf(v1.z);
      Bs[0][(r1 + 3) * 32 + b_kk] = f2bf(v1.w);
    }
  }
  __syncthreads();

  for (int s = 0; s < kcn; ++s) {
    const int cur = s & 1, nxt = cur ^ 1;
    const bool pf = (s + 1 < kcn);
    const int ktn = kc0 + s + 1;
    float4 v0, v1;
    if (pf) {
#pragma unroll
      for (int j = 0; j < 4; ++j)
        gll16(A + asrc[j] + (size_t)ktn * 32, &As[nxt][wid * 2048 + j * 512]);
      if (MODE == 0) {
        const float* p = W + (size_t)(n0 + b_row) * K + (size_t)ktn * 32 + b_c8 * 8;
        v0 = *(const float4*)p; v1 = *(const float4*)(p + 4);
      } else {
        const float* p = W + (size_t)(ktn * 32 + b_kk) * N + n0 + b_c4 * 4;
        v0 = *(const float4*)p;
        v1 = *(const float4*)(p + 32);
      }
    }
    s16x8 af[4], bf[4];
#pragma unroll
    for (int mf = 0; mf < 4; ++mf) af[mf] = *(const s16x8*)(&As[cur][0] + aoff[mf]);
#pragma unroll
    for (int nf = 0; nf < 4; ++nf) bf[nf] = *(const s16x8*)(&Bs[cur][0] + boff[nf]);
#pragma unroll
    for (int nf = 0; nf < 4; ++nf)
#pragma unroll
      for (int mf = 0; mf < 4; ++mf)
        acc[mf][nf] = mfma_bf16(af[mf], bf[nf], acc[mf][nf]);
    if (pf) {
      if (MODE == 0) {
        u32* w = (u32*)&Bs[nxt][b_row * 32 + b_c8 * 8];
        w[0] = pack2(v0.x, v0.y); w[1] = pack2(v0.z, v0.w);
        w[2] = pack2(v1.x, v1.y); w[3] = pack2(v1.z, v1.w);
      } else {
        int r0 = b_c4 * 4, r1 = 32 + b_c4 * 4;
        Bs[nxt][(r0 + 0) * 32 + b_kk] = f2bf(v0.x);
        Bs[nxt][(r0 + 1) * 32 + b_kk] = f2bf(v0.y);
        Bs[nxt][(r0 + 2) * 32 + b_kk] = f2bf(v0.z);
        Bs[nxt][(r0 + 3) * 32 + b_kk] = f2bf(v0.w);
        Bs[nxt][(r1 + 0) * 32 + b_kk] = f2bf(v1.x);
        Bs[nxt][(r1 + 1) * 32 + b_kk] = f2bf(v1.y);
        Bs[nxt][(r1 + 2) * 32 + b_kk] = f2bf(v1.z);
        Bs[nxt][(r1 + 3) * 32 + b_kk] = f2bf(v1.w);
      }
    }
    __syncthreads();
  }

  const size_t Ns = (size_t)N;
#pragma unroll
  for (int mf = 0; mf < 4; ++mf)
#pragma unroll
    for (int nf = 0; nf < 4; ++nf) {
      int col = n0 + nf * 16 + l15;
#pragma unroll
      for (int e = 0; e < 4; ++e) {
        int row = m0 + wid * 64 + mf * 16 + lg * 4 + e;
        float v = acc[mf][nf][e];
        if (atomic_mode) atomicAdd(&C[row * Ns + col], v);
        else C[row * Ns + col] = v + (bias ? bias[col] : 0.0f);
      }
    }
}

// ---------------------------------------------------------------------------
// Small kernels
// ---------------------------------------------------------------------------
__global__ __launch_bounds__(256) void k_twe(const float* __restrict__ we, u16* __restrict__ weT)
{
  __shared__ float t[32][33];
  const int n0 = blockIdx.x * 32, k0 = blockIdx.y * 32;
  const int tid = threadIdx.x;
#pragma unroll
  for (int p = 0; p < 4; ++p) {
    int e = tid + p * 256, r = e >> 5, c = e & 31;
    t[r][c] = we[(size_t)(k0 + r) * 1024 + n0 + c];
  }
  __syncthreads();
#pragma unroll
  for (int p = 0; p < 4; ++p) {
    int e = tid + p * 256, n = e >> 5, k = e & 31;
    weT[(size_t)(n0 + n) * 2048 + k0 + k] = f2bf(t[k][n]);
  }
}

__global__ void k_cast(const float* __restrict__ s, u16* __restrict__ d, int n)
{
  int i = blockIdx.x * 256 + threadIdx.x;
  if (i < n) d[i] = f2bf(s[i]);
}

__global__ void k_gather(const int* __restrict__ ids, const float* __restrict__ emb,
                         float* __restrict__ e0, u16* __restrict__ e0b)
{
  int b = blockIdx.x, tid = threadIdx.x;
  int id = ids[b];
  for (int i = tid; i < 512; i += 256) {
    float v = emb[(size_t)id * 512 + i];
    e0[(size_t)b * 512 + i] = v;
    e0b[(size_t)b * 512 + i] = f2bf(v);
  }
}

__global__ __launch_bounds__(256) void k_softmax_pred(const float* __restrict__ pred,
                                                      u16* __restrict__ probs)
{
  __shared__ float sm[4];
  const int row = blockIdx.x, tid = threadIdx.x;
  const float* x = pred + (size_t)row * 32000;
  float mx = -1e30f;
  for (int i = tid; i < 32000; i += 256) mx = fmaxf(mx, x[i]);
#pragma unroll
  for (int d = 1; d < 64; d <<= 1) mx = fmaxf(mx, __shfl_xor(mx, d));
  if ((tid & 63) == 0) sm[tid >> 6] = mx;
  __syncthreads();
  mx = fmaxf(fmaxf(sm[0], sm[1]), fmaxf(sm[2], sm[3]));
  float s = 0.f;
  for (int i = tid; i < 32000; i += 256) s += __expf(x[i] - mx);
#pragma unroll
  for (int d = 1; d < 64; d <<= 1) s += __shfl_xor(s, d);
  __syncthreads();
  if ((tid & 63) == 0) sm[tid >> 6] = s;
  __syncthreads();
  s = sm[0] + sm[1] + sm[2] + sm[3];
  float inv = 1.0f / s;
  for (int i = tid; i < 32000; i += 256)
    probs[(size_t)row * 32000 + i] = f2bf(__expf(x[i] - mx) * inv);
}

__global__ __launch_bounds__(256) void k_softmax_sc(const float* __restrict__ sc,
                                                    float* __restrict__ attn)
{
  __shared__ float sm[4];
  const int row = blockIdx.x, tid = threadIdx.x;
  float x = sc[(size_t)row * 256 + tid];
  float mx = x;
#pragma unroll
  for (int d = 1; d < 64; d <<= 1) mx = fmaxf(mx, __shfl_xor(mx, d));
  if ((tid & 63) == 0) sm[tid >> 6] = mx;
  __syncthreads();
  mx = fmaxf(fmaxf(sm[0], sm[1]), fmaxf(sm[2], sm[3]));
  float e = __expf(x - mx);
  float s = e;
#pragma unroll
  for (int d = 1; d < 64; d <<= 1) s += __shfl_xor(s, d);
  __syncthreads();
  if ((tid & 63) == 0) sm[tid >> 6] = s;
  __syncthreads();
  s = sm[0] + sm[1] + sm[2] + sm[3];
  attn[(size_t)row * 256 + tid] = e / s;
}

__global__ __launch_bounds__(256) void k_ct(const float* __restrict__ ctx,
                                            const float* __restrict__ attn,
                                            float* __restrict__ c_t)
{
  const int b = blockIdx.y;
  const int d0 = blockIdx.x * 512 + threadIdx.x * 2;
  const float2* cp = (const float2*)(ctx + (size_t)b * 524288 + d0);
  const float* ar = attn + (size_t)b * 256;
  float ax = 0.f, ay = 0.f;
#pragma unroll 4
  for (int t = 0; t < 256; ++t) {
    float a = ar[t];
    float2 v = cp[(size_t)t * 1024];
    ax += a * v.x; ay += a * v.y;
  }
  c_t[(size_t)b * 2048 + d0] = ax;
  c_t[(size_t)b * 2048 + d0 + 1] = ay;
}

__global__ void k_gate(const float* __restrict__ gepre, const float* __restrict__ b1,
                       const float* __restrict__ b2, const float* __restrict__ e0,
                       const float* __restrict__ ea, float* __restrict__ embs)
{
  int i = blockIdx.x * 256 + threadIdx.x;  // 131072
  int nn = i & 511;
  float hg = sigf(gepre[i] + b1[nn] + b2[nn]);
  embs[i] = hg * e0[i] + (1.0f - hg) * ea[i];
}

__global__ void k_cat_rnn(const float* __restrict__ embs, const float* __restrict__ ct,
                          u16* __restrict__ out)
{
  int i = blockIdx.x * 256 + threadIdx.x;  // 655360
  int m = i / 2560, c = i - m * 2560;
  float v = (c < 512) ? embs[(size_t)m * 512 + c] : ct[(size_t)m * 2048 + (c - 512)];
  out[i] = f2bf(v);
}

__global__ void k_gru(const float* __restrict__ gi, const float* __restrict__ gh,
                      const float* __restrict__ bih, const float* __restrict__ bhh,
                      const float* __restrict__ hprev, float* __restrict__ hout,
                      u16* __restrict__ hout_bf)
{
  int i = blockIdx.x * 256 + threadIdx.x;  // 262144
  int m = i >> 10, h = i & 1023;
  const float* gim = gi + (size_t)m * 3072;
  const float* ghm = gh + (size_t)m * 3072;
  float r = sigf(gim[h] + bih[h] + ghm[h] + bhh[h]);
  float z = sigf(gim[1024 + h] + bih[1024 + h] + ghm[1024 + h] + bhh[1024 + h]);
  float n = tanhf(gim[2048 + h] + bih[2048 + h] + r * (ghm[2048 + h] + bhh[2048 + h]));
  float hv = (1.0f - z) * n + z * hprev[i];
  hout[i] = hv;
  if (hout_bf) hout_bf[i] = f2bf(hv);
}

__global__ void k_cat_bn0(const float* __restrict__ h11, const float* __restrict__ ct,
                          const float* __restrict__ embs, u16* __restrict__ out)
{
  int i = blockIdx.x * 256 + threadIdx.x;  // 917504
  int m = i / 3584, c = i - m * 3584;
  float v;
  if (c < 1024) v = h11[(size_t)m * 1024 + c];
  else if (c < 3072) v = ct[(size_t)m * 2048 + (c - 1024)];
  else v = embs[(size_t)m * 512 + (c - 3072)];
  out[i] = f2bf(v);
}

__global__ void k_bn0(const float* __restrict__ pre, const float* __restrict__ bias,
                      u16* __restrict__ b0b)
{
  int i = blockIdx.x * 256 + threadIdx.x;  // 131072
  int nn = i & 511;
  b0b[i] = f2bf(tanhf(pre[i] + bias[nn]));
}

__global__ void k_mask(const int* __restrict__ mask, float* __restrict__ pred)
{
  int t = blockIdx.x * 256 + threadIdx.x;  // 2048
  if (t >= 2048) return;
  int b = t >> 3;
  int col = mask[t];
  if (col != 0 && col != 3) pred[(size_t)b * 32000 + col] = -10000000.0f;
}

// ---------------------------------------------------------------------------
// Launch
// ---------------------------------------------------------------------------
extern "C" void kernel_launch(void* const* d_in, const int* in_sizes, int n_in,
                              void* d_out, int out_size, void* d_ws, size_t ws_size,
                              hipStream_t stream)
{
  const int*   input_ids = (const int*)d_in[0];
  const float* prediction= (const float*)d_in[1];
  const float* context   = (const float*)d_in[2];
  const float* h0        = (const float*)d_in[3];
  const int*   maskp     = (const int*)d_in[4];
  const float* embedding = (const float*)d_in[5];
  const float* ge1_w = (const float*)d_in[6];
  const float* ge1_b = (const float*)d_in[7];
  const float* ge2_w = (const float*)d_in[8];
  const float* ge2_b = (const float*)d_in[9];
  const float* att_we = (const float*)d_in[10];
  const float* att_wd = (const float*)d_in[11];
  const float* att_v  = (const float*)d_in[12];
  const float* wih0 = (const float*)d_in[13];
  const float* whh0 = (const float*)d_in[14];
  const float* bih0 = (const float*)d_in[15];
  const float* bhh0 = (const float*)d_in[16];
  const float* wih1 = (const float*)d_in[17];
  const float* whh1 = (const float*)d_in[18];
  const float* bih1 = (const float*)d_in[19];
  const float* bhh1 = (const float*)d_in[20];
  const float* bn0_w = (const float*)d_in[21];
  const float* bn0_b = (const float*)d_in[22];
  const float* bn1_w = (const float*)d_in[23];
  const float* bn1_b = (const float*)d_in[24];

  float* out = (float*)d_out;
  float* out_pred = out;                    // 256*32000
  float* out_h1_0 = out + 8192000;          // 256*1024
  float* out_h1_1 = out + 8454144;          // 256*1024
  float* out_attn = out + 8716288;          // 256*256

  char* ws = (char*)d_ws;
  // memset region (split-K atomic targets)
  float* qd      = (float*)(ws + 0);         // 1048576 B
  float* emb_avg = (float*)(ws + 1048576);   // 524288
  float* gepre   = (float*)(ws + 1572864);   // 524288
  float* gi0     = (float*)(ws + 2097152);   // 3145728
  float* gh0     = (float*)(ws + 5242880);   // 3145728
  float* gi1     = (float*)(ws + 8388608);   // 3145728
  float* gh1     = (float*)(ws + 11534336);  // 3145728
  float* bn0pre  = (float*)(ws + 14680064);  // 524288
  const size_t MS_BYTES = 15204352;
  // non-memset
  float* scores  = (float*)(ws + 15204352);  // 262144
  float* c_t     = (float*)(ws + 15466496);  // 2097152
  float* embs0   = (float*)(ws + 17563648);  // 524288
  float* embs    = (float*)(ws + 18087936);  // 524288
  u16* weT       = (u16*)(ws + 18612224);    // 4194304
  u16* h0_bf     = (u16*)(ws + 22806528);    // 1048576
  u16* embs0_bf  = (u16*)(ws + 23855104);    // 262144
  u16* probs_bf  = (u16*)(ws + 24117248);    // 16384000
  u16* embavg_bf = (u16*)(ws + 40501248);    // 262144
  u16* rnnin_bf  = (u16*)(ws + 40763392);    // 1310720
  u16* h1_0_bf   = (u16*)(ws + 42074112);    // 524288
  u16* bn0in_bf  = (u16*)(ws + 42598400);    // 1835008
  u16* b0_bf     = (u16*)(ws + 44433408);    // 262144

  (void)in_sizes; (void)n_in; (void)out_size; (void)ws_size;

  hipMemsetAsync(ws, 0, MS_BYTES, stream);

  // prep
  k_twe<<<dim3(32, 64), 256, 0, stream>>>(att_we, weT);
  k_cast<<<2048, 256, 0, stream>>>(h0, h0_bf, 524288);
  k_gather<<<256, 256, 0, stream>>>(input_ids, embedding, embs0, embs0_bf);
  k_softmax_pred<<<256, 256, 0, stream>>>(prediction, probs_bf);

  // qd = h0[1] @ att_wd   (MODE1, atomic split-K x4)
  k_gemm<1><<<dim3(1, 16, 4), 256, 0, stream>>>(h0_bf + 262144, att_wd, qd, nullptr,
                                                1024, 1024, 8, 32, 1);
  // big fused attention-scores kernel
  k_scores<<<1024, 512, SCORES_LDS, stream>>>(context, weT, qd, att_v, scores);

  // emb_avg = probs @ embedding (MODE1, split-K x25)
  k_gemm<1><<<dim3(1, 8, 25), 256, 0, stream>>>(probs_bf, embedding, emb_avg, nullptr,
                                                512, 32000, 40, 1000, 1);
  k_cast<<<512, 256, 0, stream>>>(emb_avg, embavg_bf, 131072);
  // gepre = embs0@ge1_w + emb_avg@ge2_w
  k_gemm<1><<<dim3(1, 8, 2), 256, 0, stream>>>(embs0_bf, ge1_w, gepre, nullptr,
                                               512, 512, 8, 16, 1);
  k_gemm<1><<<dim3(1, 8, 2), 256, 0, stream>>>(embavg_bf, ge2_w, gepre, nullptr,
                                               512, 512, 8, 16, 1);
  k_gate<<<512, 256, 0, stream>>>(gepre, ge1_b, ge2_b, embs0, emb_avg, embs);

  // attention softmax + context reduction
  k_softmax_sc<<<256, 256, 0, stream>>>(scores, out_attn);
  k_ct<<<dim3(4, 256), 256, 0, stream>>>(context, out_attn, c_t);

  // GRU layer 0
  k_cat_rnn<<<2560, 256, 0, stream>>>(embs, c_t, rnnin_bf);
  k_gemm<0><<<dim3(1, 48, 2), 256, 0, stream>>>(rnnin_bf, wih0, gi0, nullptr,
                                                3072, 2560, 40, 80, 1);
  k_gemm<0><<<dim3(1, 48, 2), 256, 0, stream>>>(h0_bf, whh0, gh0, nullptr,
                                                3072, 1024, 16, 32, 1);
  k_gru<<<1024, 256, 0, stream>>>(gi0, gh0, bih0, bhh0, h0, out_h1_0, h1_0_bf);
  // GRU layer 1
  k_gemm<0><<<dim3(1, 48, 2), 256, 0, stream>>>(h1_0_bf, wih1, gi1, nullptr,
                                                3072, 1024, 16, 32, 1);
  k_gemm<0><<<dim3(1, 48, 2), 256, 0, stream>>>(h0_bf + 262144, whh1, gh1, nullptr,
                                                3072, 1024, 16, 32, 1);
  k_gru<<<1024, 256, 0, stream>>>(gi1, gh1, bih1, bhh1, h0 + 262144, out_h1_1, nullptr);

  // bottleneck + output projection
  k_cat_bn0<<<3584, 256, 0, stream>>>(out_h1_1, c_t, embs, bn0in_bf);
  k_gemm<1><<<dim3(1, 8, 8), 256, 0, stream>>>(bn0in_bf, bn0_w, bn0pre, nullptr,
                                               512, 3584, 14, 112, 1);
  k_bn0<<<512, 256, 0, stream>>>(bn0pre, bn0_b, b0_bf);
  k_gemm<1><<<dim3(1, 500, 1), 256, 0, stream>>>(b0_bf, bn1_w, out_pred, bn1_b,
                                                 32000, 512, 16, 16, 0);
  k_mask<<<8, 256, 0, stream>>>(maskp, out_pred);
}